// Round 18
// baseline (73.542 us; speedup 1.0000x reference)
//
#include <hip/hip_runtime.h>
#include <hip/hip_bf16.h>

// LoRA-GCN: out = propagate(x @ W_B^T @ W_A^T) + bias
// Rank-3 fusion: propagate z = x @ W_B^T (N x 3), apply W_A^T after.
// R18: R15 structure (70.7us best) with CHUNK 4096 -> 8192 (196 bin blocks,
//      32 edges/thread @256): write runs 2x longer (coalescing), gcur rounds
//      halved, per-block fixed costs amortized. LDS 36.2KB -> 16 waves/CU,
//      which R16 proved is not the binding constraint (32 waves regressed).
// Falsified: scattered-store bin (R2), coop grid (R8), interleave (R9),
// WB amortize (R11), atomic-free seg (R12), split K1 (R13: fused ~7us win),
// CHUNK 2048 (R7), 512-thread K1 (R16). Marginal: K2 width (R14), LDS
// replication (R15).

#define RANK 3
#define IN_DIM 256
#define OUT_DIM 64

#define NB    256         // sub-buckets
#define BS    392         // nodes per sub-bucket (256*392 = 100352 >= N), < 512
#define CAP2  8192        // per-sub-bucket record capacity (avg ~6.1k, +34%)
#define CHUNK 8192        // edges per binning block (32 per thread @256) - R18
#define EPT   32          // edges per thread in bin branch

// ---------------------------------------------------------------------------
// K1: fused. Blocks [0,nbin): counting-sort binning. Blocks [nbin,...):
//     zproj, 16 lanes per node.
__global__ void k1_zproj_bin(const float* __restrict__ x,
                             const float* __restrict__ WB,     // [3][256]
                             float4* __restrict__ z4, int N,
                             const int* __restrict__ idx, int E, int nsample,
                             unsigned* __restrict__ recs, int* __restrict__ gcur,
                             int nbin) {
    __shared__ int s_hist[NB];
    __shared__ int s_lbase[NB];
    __shared__ int s_base[NB];
    __shared__ int s_rank[NB];
    __shared__ int s_wsum[4];
    __shared__ int s_nz;
    __shared__ unsigned s_buf[CHUNK];

    if ((int)blockIdx.x < nbin) {
        // ---- bin branch (256 threads, 32 edges each) ----
        if (threadIdx.x == 0) s_nz = 0;
        { int t = threadIdx.x; s_hist[t] = 0; s_rank[t] = 0; }   // blockDim == NB
        __syncthreads();
        int nz = 0;
        for (int i = threadIdx.x; i < nsample; i += 256) nz |= idx[2 * i + 1];
        if (nz) s_nz = 1;                    // benign race
        __syncthreads();
        const int stride = (s_nz == 0) ? 2 : 1;
        const int* rowp = idx;
        const int* colp = idx + (size_t)E * stride;
        const int e0 = blockIdx.x * CHUNK;

        int er[EPT], ec[EPT];
        #pragma unroll
        for (int k = 0; k < EPT; ++k) {
            int e = e0 + k * 256 + (int)threadIdx.x;
            er[k] = 0; ec[k] = 0;            // sentinel r==c -> skipped
            if (e < E) {
                if (stride == 2) {
                    er[k] = reinterpret_cast<const int2*>(rowp)[e].x;
                    ec[k] = reinterpret_cast<const int2*>(colp)[e].x;
                } else {
                    er[k] = rowp[e];
                    ec[k] = colp[e];
                }
            }
        }
        #pragma unroll
        for (int k = 0; k < EPT; ++k)
            if (er[k] != ec[k]) atomicAdd(&s_hist[ec[k] / BS], 1);
        __syncthreads();

        // 256-entry exclusive scan: 4-wave shuffle scan + cross-wave offsets
        {
            int t = threadIdx.x;             // == bucket id
            int v = s_hist[t];
            int incl = v;
            #pragma unroll
            for (int d = 1; d < 64; d <<= 1) {
                int o = __shfl_up(incl, d);
                if ((t & 63) >= d) incl += o;
            }
            if ((t & 63) == 63) s_wsum[t >> 6] = incl;
            __syncthreads();
            int woff = 0;
            #pragma unroll
            for (int w = 0; w < 4; ++w) if (w < (t >> 6)) woff += s_wsum[w];
            s_lbase[t] = woff + incl - v;
            s_base[t]  = v ? atomicAdd(&gcur[t], v) : 0;
        }
        __syncthreads();

        #pragma unroll
        for (int k = 0; k < EPT; ++k) {
            if (er[k] != ec[k]) {
                int b = ec[k] / BS;
                int pos = s_lbase[b] + atomicAdd(&s_rank[b], 1);
                s_buf[pos] = ((unsigned)er[k] << 9) | (unsigned)(ec[k] - b * BS);
            }
        }
        __syncthreads();

        int total = s_lbase[NB - 1] + s_hist[NB - 1];
        for (int i = threadIdx.x; i < total; i += 256) {
            int lo = 0, hi = NB - 1;         // largest b with lbase[b] <= i
            #pragma unroll
            for (int s = 0; s < 8; ++s) {
                int mid = (lo + hi + 1) >> 1;
                if (s_lbase[mid] <= i) lo = mid; else hi = mid - 1;
            }
            int rel = s_base[lo] + (i - s_lbase[lo]);
            if (rel < CAP2)
                recs[(size_t)lo * CAP2 + rel] = s_buf[i];
        }
        return;
    }

    // ---- zproj branch: 16 lanes per node ----
    int gtid = (blockIdx.x - nbin) * blockDim.x + threadIdx.x;
    int node = gtid >> 4;
    int l = threadIdx.x & 15;
    if (node >= N) return;

    const float4* xr = reinterpret_cast<const float4*>(x + (size_t)node * IN_DIM);
    const float4* wb0 = reinterpret_cast<const float4*>(WB);
    const float4* wb1 = reinterpret_cast<const float4*>(WB + IN_DIM);
    const float4* wb2 = reinterpret_cast<const float4*>(WB + 2 * IN_DIM);

    float p0 = 0.f, p1 = 0.f, p2 = 0.f;
    #pragma unroll
    for (int j = 0; j < 4; ++j) {
        int c = j * 16 + l;                  // group reads 256B contiguous
        float4 xv = xr[c];
        float4 w0 = wb0[c];
        float4 w1 = wb1[c];
        float4 w2 = wb2[c];
        p0 += xv.x * w0.x + xv.y * w0.y + xv.z * w0.z + xv.w * w0.w;
        p1 += xv.x * w1.x + xv.y * w1.y + xv.z * w1.z + xv.w * w1.w;
        p2 += xv.x * w2.x + xv.y * w2.y + xv.z * w2.z + xv.w * w2.w;
    }
    #pragma unroll
    for (int m = 8; m > 0; m >>= 1) {        // reduce within 16-lane group
        p0 += __shfl_xor(p0, m);
        p1 += __shfl_xor(p1, m);
        p2 += __shfl_xor(p2, m);
    }
    if (l == 0) z4[node] = make_float4(p0, p1, p2, 0.0f);
}

// ---------------------------------------------------------------------------
// K2: one block per sub-bucket, 1024 threads, 4-way replicated s_deg; fold;
// zw[n] = (dinv*z, dinv), dinv = rsqrt(deg+1).  (R15)
__global__ void __launch_bounds__(1024) k2_zw(
        const unsigned* __restrict__ recs, const int* __restrict__ gcur,
        const float4* __restrict__ z4, float4* __restrict__ zw, int N) {
    __shared__ int s_deg[4][BS];
    int b = blockIdx.x;
    int rep = threadIdx.x >> 8;              // 0..3
    {
        int* sd = &s_deg[0][0];
        for (int j = threadIdx.x; j < 4 * BS; j += 1024) sd[j] = 0;
    }
    __syncthreads();
    int cnt = gcur[b]; if (cnt > CAP2) cnt = CAP2;
    const unsigned* rb = recs + (size_t)b * CAP2;
    for (int i = threadIdx.x; i < cnt; i += 1024)
        atomicAdd(&s_deg[rep][rb[i] & 511u], 1);
    __syncthreads();
    if (threadIdx.x < BS) {
        int n = b * BS + (int)threadIdx.x;
        if (n < N) {
            int d = s_deg[0][threadIdx.x] + s_deg[1][threadIdx.x]
                  + s_deg[2][threadIdx.x] + s_deg[3][threadIdx.x];
            float di = rsqrtf((float)d + 1.0f);
            float4 zn = z4[n];
            zw[n] = make_float4(di * zn.x, di * zn.y, di * zn.z, di);
        }
    }
}

// ---------------------------------------------------------------------------
// K3: one block per sub-bucket, 4-way replicated s_agg; fold + fused
// epilogue: a = zw[n].w*(sum + zw[n].xyz); out[n][:] = a . W_A + bias.  (R15)
__global__ void __launch_bounds__(1024) k3_aggout(
        const unsigned* __restrict__ recs, const int* __restrict__ gcur,
        const float4* __restrict__ zw,
        const float* __restrict__ WA,   // [64][3]
        const float* __restrict__ bias,
        float* __restrict__ out, int N) {
    __shared__ float s_agg[4][BS * 3];       // 18.8 KB
    __shared__ float s_wa0[64], s_wa1[64], s_wa2[64], s_bb[64];
    int b = blockIdx.x;
    int rep = threadIdx.x >> 8;              // 0..3

    {
        float* sa = &s_agg[0][0];
        for (int j = threadIdx.x; j < 4 * BS * 3; j += 1024) sa[j] = 0.0f;
    }
    if (threadIdx.x < 64) {
        int j = threadIdx.x;
        s_wa0[j] = WA[j * 3 + 0];
        s_wa1[j] = WA[j * 3 + 1];
        s_wa2[j] = WA[j * 3 + 2];
        s_bb[j]  = bias[j];
    }
    __syncthreads();

    int cnt = gcur[b]; if (cnt > CAP2) cnt = CAP2;
    const unsigned* rb = recs + (size_t)b * CAP2;
    float* sa = &s_agg[rep][0];
    for (int i = threadIdx.x; i < cnt; i += 1024) {
        unsigned rc = rb[i];
        int cl = (int)(rc & 511u);
        float4 zr = zw[rc >> 9];
        atomicAdd(&sa[cl * 3 + 0], zr.x);
        atomicAdd(&sa[cl * 3 + 1], zr.y);
        atomicAdd(&sa[cl * 3 + 2], zr.z);
    }
    __syncthreads();

    if (threadIdx.x < BS) {
        int t = threadIdx.x;
        int n = b * BS + t;
        if (n < N) {
            float4 zn = zw[n];
            float di = zn.w;
            float a0 = s_agg[0][t*3+0] + s_agg[1][t*3+0] + s_agg[2][t*3+0] + s_agg[3][t*3+0];
            float a1 = s_agg[0][t*3+1] + s_agg[1][t*3+1] + s_agg[2][t*3+1] + s_agg[3][t*3+1];
            float a2 = s_agg[0][t*3+2] + s_agg[1][t*3+2] + s_agg[2][t*3+2] + s_agg[3][t*3+2];
            s_agg[0][t*3+0] = di * (a0 + zn.x);
            s_agg[0][t*3+1] = di * (a1 + zn.y);
            s_agg[0][t*3+2] = di * (a2 + zn.z);
        }
    }
    __syncthreads();

    for (int i = threadIdx.x; i < BS * 16; i += 1024) {
        int nl = i >> 4, j4 = (i & 15) << 2;
        int n = b * BS + nl;
        if (n >= N) continue;
        float a0 = s_agg[0][nl*3+0], a1 = s_agg[0][nl*3+1], a2 = s_agg[0][nl*3+2];
        float4 o;
        o.x = a0 * s_wa0[j4+0] + a1 * s_wa1[j4+0] + a2 * s_wa2[j4+0] + s_bb[j4+0];
        o.y = a0 * s_wa0[j4+1] + a1 * s_wa1[j4+1] + a2 * s_wa2[j4+1] + s_bb[j4+1];
        o.z = a0 * s_wa0[j4+2] + a1 * s_wa1[j4+2] + a2 * s_wa2[j4+2] + s_bb[j4+2];
        o.w = a0 * s_wa0[j4+3] + a1 * s_wa1[j4+3] + a2 * s_wa2[j4+3] + s_bb[j4+3];
        *reinterpret_cast<float4*>(out + (size_t)n * OUT_DIM + j4) = o;
    }
}

// ---------------------------------------------------------------------------
// Fallback (R1 path, shape-robust): detect + global-atomic deg/scatter + out.
__global__ void detect_kernel(const int* __restrict__ idx, int nsample, int* flag) {
    __shared__ int s_nz;
    if (threadIdx.x == 0) s_nz = 0;
    __syncthreads();
    int nz = 0;
    for (int i = threadIdx.x; i < nsample; i += blockDim.x) nz |= idx[2 * i + 1];
    if (nz) s_nz = 1;
    __syncthreads();
    if (threadIdx.x == 0) *flag = (s_nz == 0) ? 1 : 0;
}
__global__ void deg_kernel(const int* __restrict__ idx, int E,
                           const int* __restrict__ flag, float* __restrict__ deg) {
    int stride = (*flag) ? 2 : 1;
    const int* rowp = idx;
    const int* colp = idx + (size_t)E * stride;
    int step = gridDim.x * blockDim.x;
    for (int e = blockIdx.x * blockDim.x + threadIdx.x; e < E; e += step) {
        int r = rowp[(size_t)e * stride];
        int c = colp[(size_t)e * stride];
        if (r != c) atomicAdd(&deg[c], 1.0f);
    }
}
__global__ void dinv_self_kernel(const float4* __restrict__ z4, const float* __restrict__ deg,
                                 float* __restrict__ dinv, float* __restrict__ agg, int N) {
    int n = blockIdx.x * blockDim.x + threadIdx.x;
    if (n >= N) return;
    float d = deg[n] + 1.0f;
    float di = rsqrtf(d);
    dinv[n] = di;
    float w = 1.0f / d;
    float4 zn = z4[n];
    agg[(size_t)n * 3 + 0] = w * zn.x;
    agg[(size_t)n * 3 + 1] = w * zn.y;
    agg[(size_t)n * 3 + 2] = w * zn.z;
}
__global__ void scatter_kernel(const int* __restrict__ idx, int E,
                               const int* __restrict__ flag,
                               const float4* __restrict__ z4,
                               const float* __restrict__ dinv,
                               float* __restrict__ agg) {
    int stride = (*flag) ? 2 : 1;
    const int* rowp = idx;
    const int* colp = idx + (size_t)E * stride;
    int step = gridDim.x * blockDim.x;
    for (int e = blockIdx.x * blockDim.x + threadIdx.x; e < E; e += step) {
        int r = rowp[(size_t)e * stride];
        int c = colp[(size_t)e * stride];
        if (r != c) {
            float w = dinv[r] * dinv[c];
            float4 zr = z4[r];
            atomicAdd(&agg[(size_t)c * 3 + 0], w * zr.x);
            atomicAdd(&agg[(size_t)c * 3 + 1], w * zr.y);
            atomicAdd(&agg[(size_t)c * 3 + 2], w * zr.z);
        }
    }
}
__global__ void out_kernel(const float* __restrict__ agg,
                           const float* __restrict__ WA,
                           const float* __restrict__ bias,
                           float* __restrict__ out, int N) {
    int t = blockIdx.x * blockDim.x + threadIdx.x;
    int n = t >> 6;
    int j = t & 63;
    if (n >= N) return;
    float a0 = agg[(size_t)n * 3 + 0];
    float a1 = agg[(size_t)n * 3 + 1];
    float a2 = agg[(size_t)n * 3 + 2];
    out[(size_t)n * OUT_DIM + j] =
        a0 * WA[j * 3 + 0] + a1 * WA[j * 3 + 1] + a2 * WA[j * 3 + 2] + bias[j];
}

extern "C" void kernel_launch(void* const* d_in, const int* in_sizes, int n_in,
                              void* d_out, int out_size, void* d_ws, size_t ws_size,
                              hipStream_t stream) {
    const float* x    = (const float*)d_in[0];
    const int*   idx  = (const int*)d_in[1];
    const float* WB   = (const float*)d_in[2];
    const float* WA   = (const float*)d_in[3];
    const float* bias = (const float*)d_in[4];
    float* out = (float*)d_out;

    const int N = in_sizes[0] / IN_DIM;     // 100000
    const int E = in_sizes[1] / 2;          // 1600000

    auto align256 = [](size_t o) { return (o + 255) & ~(size_t)255; };
    char* ws = (char*)d_ws;
    size_t off = 0;
    int*    flag = (int*)(ws + off);    off = align256(off + sizeof(int));
    int*    gcur = (int*)(ws + off);    off = align256(off + NB * sizeof(int));
    float4* z4   = (float4*)(ws + off); off = align256(off + (size_t)N * sizeof(float4));
    float4* zw   = (float4*)(ws + off); off = align256(off + (size_t)N * sizeof(float4));
    float*  dinv = (float*)(ws + off);  off = align256(off + (size_t)N * sizeof(float));
    unsigned* recs = (unsigned*)(ws + off); off = align256(off + (size_t)NB * CAP2 * sizeof(unsigned));
    // fallback reuses fast-path regions
    float* degF = (float*)zw;
    float* aggF = (float*)recs;            // N*3 floats fit in recs region (8MB)

    const bool fast = (N <= NB * BS) && (N < (1 << 23)) && (ws_size >= off);

    int nsample = E < 1024 ? E : 1024;

    if (fast) {
        hipMemsetAsync(gcur, 0, NB * sizeof(int), stream);
        int nbin = (E + CHUNK - 1) / CHUNK;
        int nzp  = (N + 15) / 16;           // 16 nodes per 256-thread block
        k1_zproj_bin<<<nbin + nzp, 256, 0, stream>>>(x, WB, z4, N, idx, E, nsample,
                                                     recs, gcur, nbin);
        k2_zw<<<NB, 1024, 0, stream>>>(recs, gcur, z4, zw, N);
        k3_aggout<<<NB, 1024, 0, stream>>>(recs, gcur, zw, WA, bias, out, N);
    } else {
        detect_kernel<<<1, 256, 0, stream>>>(idx, nsample, flag);
        k1_zproj_bin<<<(N + 15) / 16, 256, 0, stream>>>(x, WB, z4, N, idx, E, nsample,
                                                        (unsigned*)aggF, gcur, 0);
        hipMemsetAsync(degF, 0, (size_t)N * sizeof(float), stream);
        deg_kernel<<<2048, 256, 0, stream>>>(idx, E, flag, degF);
        dinv_self_kernel<<<(N + 255) / 256, 256, 0, stream>>>(z4, degF, dinv, aggF, N);
        scatter_kernel<<<2048, 256, 0, stream>>>(idx, E, flag, z4, dinv, aggF);
        long long total = (long long)N * OUT_DIM;
        out_kernel<<<(int)((total + 255) / 256), 256, 0, stream>>>(aggF, WA, bias, out, N);
    }
}

// Round 19
// 70.553 us; speedup vs baseline: 1.0424x; 1.0424x over previous
//
#include <hip/hip_runtime.h>
#include <hip/hip_bf16.h>

// LoRA-GCN: out = propagate(x @ W_B^T @ W_A^T) + bias
// Rank-3 fusion: propagate z = x @ W_B^T (N x 3), apply W_A^T after.
// R19: EXACT RESTORE of R15 (70.7us session best). Converged configuration:
//  K1 fused (bin-first, CHUNK 4096, 256 thr) + 16-lane zproj;
//  K2 1024 thr, 4-way replicated s_deg -> zw = (dinv*z, dinv);
//  K3 1024 thr, 4-way replicated s_agg + fused W_A epilogue.
// Falsified levers: scattered-store bin (R2), coop grid (R8), interleave (R9),
// WB amortize (R11), atomic-free seg (R12), split K1 (R13), CHUNK 2048/8192
// (R7/R18), 512-thr K1 (R16). Remaining time = ~30us bytes + issue-bound
// zproj + 3-phase dependency chain + dispatch drains.

#define RANK 3
#define IN_DIM 256
#define OUT_DIM 64

#define NB    256         // sub-buckets
#define BS    392         // nodes per sub-bucket (256*392 = 100352 >= N), < 512
#define CAP2  8192        // per-sub-bucket record capacity (avg ~6.1k, +34%)
#define CHUNK 4096        // edges per binning block (16 per thread @256) - proven

// ---------------------------------------------------------------------------
// K1: fused. Blocks [0,nbin): counting-sort binning. Blocks [nbin,...):
//     zproj, 16 lanes per node.
__global__ void k1_zproj_bin(const float* __restrict__ x,
                             const float* __restrict__ WB,     // [3][256]
                             float4* __restrict__ z4, int N,
                             const int* __restrict__ idx, int E, int nsample,
                             unsigned* __restrict__ recs, int* __restrict__ gcur,
                             int nbin) {
    __shared__ int s_hist[NB];
    __shared__ int s_lbase[NB];
    __shared__ int s_base[NB];
    __shared__ int s_rank[NB];
    __shared__ int s_wsum[4];
    __shared__ int s_nz;
    __shared__ unsigned s_buf[CHUNK];

    if ((int)blockIdx.x < nbin) {
        // ---- bin branch ----
        if (threadIdx.x == 0) s_nz = 0;
        { int t = threadIdx.x; s_hist[t] = 0; s_rank[t] = 0; }   // blockDim == NB
        __syncthreads();
        int nz = 0;
        for (int i = threadIdx.x; i < nsample; i += 256) nz |= idx[2 * i + 1];
        if (nz) s_nz = 1;                    // benign race
        __syncthreads();
        const int stride = (s_nz == 0) ? 2 : 1;
        const int* rowp = idx;
        const int* colp = idx + (size_t)E * stride;
        const int e0 = blockIdx.x * CHUNK;

        int er[16], ec[16];
        #pragma unroll
        for (int k = 0; k < 16; ++k) {
            int e = e0 + k * 256 + (int)threadIdx.x;
            er[k] = 0; ec[k] = 0;            // sentinel r==c -> skipped
            if (e < E) {
                if (stride == 2) {
                    er[k] = reinterpret_cast<const int2*>(rowp)[e].x;
                    ec[k] = reinterpret_cast<const int2*>(colp)[e].x;
                } else {
                    er[k] = rowp[e];
                    ec[k] = colp[e];
                }
            }
        }
        #pragma unroll
        for (int k = 0; k < 16; ++k)
            if (er[k] != ec[k]) atomicAdd(&s_hist[ec[k] / BS], 1);
        __syncthreads();

        // 256-entry exclusive scan: 4-wave shuffle scan + cross-wave offsets
        {
            int t = threadIdx.x;             // == bucket id
            int v = s_hist[t];
            int incl = v;
            #pragma unroll
            for (int d = 1; d < 64; d <<= 1) {
                int o = __shfl_up(incl, d);
                if ((t & 63) >= d) incl += o;
            }
            if ((t & 63) == 63) s_wsum[t >> 6] = incl;
            __syncthreads();
            int woff = 0;
            #pragma unroll
            for (int w = 0; w < 4; ++w) if (w < (t >> 6)) woff += s_wsum[w];
            s_lbase[t] = woff + incl - v;
            s_base[t]  = v ? atomicAdd(&gcur[t], v) : 0;
        }
        __syncthreads();

        #pragma unroll
        for (int k = 0; k < 16; ++k) {
            if (er[k] != ec[k]) {
                int b = ec[k] / BS;
                int pos = s_lbase[b] + atomicAdd(&s_rank[b], 1);
                s_buf[pos] = ((unsigned)er[k] << 9) | (unsigned)(ec[k] - b * BS);
            }
        }
        __syncthreads();

        int total = s_lbase[NB - 1] + s_hist[NB - 1];
        for (int i = threadIdx.x; i < total; i += 256) {
            int lo = 0, hi = NB - 1;         // largest b with lbase[b] <= i
            #pragma unroll
            for (int s = 0; s < 8; ++s) {
                int mid = (lo + hi + 1) >> 1;
                if (s_lbase[mid] <= i) lo = mid; else hi = mid - 1;
            }
            int rel = s_base[lo] + (i - s_lbase[lo]);
            if (rel < CAP2)
                recs[(size_t)lo * CAP2 + rel] = s_buf[i];
        }
        return;
    }

    // ---- zproj branch: 16 lanes per node ----
    int gtid = (blockIdx.x - nbin) * blockDim.x + threadIdx.x;
    int node = gtid >> 4;
    int l = threadIdx.x & 15;
    if (node >= N) return;

    const float4* xr = reinterpret_cast<const float4*>(x + (size_t)node * IN_DIM);
    const float4* wb0 = reinterpret_cast<const float4*>(WB);
    const float4* wb1 = reinterpret_cast<const float4*>(WB + IN_DIM);
    const float4* wb2 = reinterpret_cast<const float4*>(WB + 2 * IN_DIM);

    float p0 = 0.f, p1 = 0.f, p2 = 0.f;
    #pragma unroll
    for (int j = 0; j < 4; ++j) {
        int c = j * 16 + l;                  // group reads 256B contiguous
        float4 xv = xr[c];
        float4 w0 = wb0[c];
        float4 w1 = wb1[c];
        float4 w2 = wb2[c];
        p0 += xv.x * w0.x + xv.y * w0.y + xv.z * w0.z + xv.w * w0.w;
        p1 += xv.x * w1.x + xv.y * w1.y + xv.z * w1.z + xv.w * w1.w;
        p2 += xv.x * w2.x + xv.y * w2.y + xv.z * w2.z + xv.w * w2.w;
    }
    #pragma unroll
    for (int m = 8; m > 0; m >>= 1) {        // reduce within 16-lane group
        p0 += __shfl_xor(p0, m);
        p1 += __shfl_xor(p1, m);
        p2 += __shfl_xor(p2, m);
    }
    if (l == 0) z4[node] = make_float4(p0, p1, p2, 0.0f);
}

// ---------------------------------------------------------------------------
// K2: one block per sub-bucket, 1024 threads, 4-way replicated s_deg:
// each 256-thread group accumulates its own histogram replica; fold; then
// zw[n] = (dinv*z, dinv) with dinv = rsqrt(deg+1).
__global__ void __launch_bounds__(1024) k2_zw(
        const unsigned* __restrict__ recs, const int* __restrict__ gcur,
        const float4* __restrict__ z4, float4* __restrict__ zw, int N) {
    __shared__ int s_deg[4][BS];
    int b = blockIdx.x;
    int rep = threadIdx.x >> 8;              // 0..3
    {
        int* sd = &s_deg[0][0];
        for (int j = threadIdx.x; j < 4 * BS; j += 1024) sd[j] = 0;
    }
    __syncthreads();
    int cnt = gcur[b]; if (cnt > CAP2) cnt = CAP2;
    const unsigned* rb = recs + (size_t)b * CAP2;
    for (int i = threadIdx.x; i < cnt; i += 1024)
        atomicAdd(&s_deg[rep][rb[i] & 511u], 1);
    __syncthreads();
    if (threadIdx.x < BS) {
        int n = b * BS + (int)threadIdx.x;
        if (n < N) {
            int d = s_deg[0][threadIdx.x] + s_deg[1][threadIdx.x]
                  + s_deg[2][threadIdx.x] + s_deg[3][threadIdx.x];
            float di = rsqrtf((float)d + 1.0f);
            float4 zn = z4[n];
            zw[n] = make_float4(di * zn.x, di * zn.y, di * zn.z, di);
        }
    }
}

// ---------------------------------------------------------------------------
// K3: one block per sub-bucket, 4-way replicated s_agg; fold + fused
// epilogue: a = zw[n].w*(sum + zw[n].xyz); out[n][:] = a . W_A + bias.
__global__ void __launch_bounds__(1024) k3_aggout(
        const unsigned* __restrict__ recs, const int* __restrict__ gcur,
        const float4* __restrict__ zw,
        const float* __restrict__ WA,   // [64][3]
        const float* __restrict__ bias,
        float* __restrict__ out, int N) {
    __shared__ float s_agg[4][BS * 3];       // 18.8 KB
    __shared__ float s_wa0[64], s_wa1[64], s_wa2[64], s_bb[64];
    int b = blockIdx.x;
    int rep = threadIdx.x >> 8;              // 0..3

    {
        float* sa = &s_agg[0][0];
        for (int j = threadIdx.x; j < 4 * BS * 3; j += 1024) sa[j] = 0.0f;
    }
    if (threadIdx.x < 64) {
        int j = threadIdx.x;
        s_wa0[j] = WA[j * 3 + 0];
        s_wa1[j] = WA[j * 3 + 1];
        s_wa2[j] = WA[j * 3 + 2];
        s_bb[j]  = bias[j];
    }
    __syncthreads();

    int cnt = gcur[b]; if (cnt > CAP2) cnt = CAP2;
    const unsigned* rb = recs + (size_t)b * CAP2;
    float* sa = &s_agg[rep][0];
    for (int i = threadIdx.x; i < cnt; i += 1024) {
        unsigned rc = rb[i];
        int cl = (int)(rc & 511u);
        float4 zr = zw[rc >> 9];
        atomicAdd(&sa[cl * 3 + 0], zr.x);
        atomicAdd(&sa[cl * 3 + 1], zr.y);
        atomicAdd(&sa[cl * 3 + 2], zr.z);
    }
    __syncthreads();

    if (threadIdx.x < BS) {
        int t = threadIdx.x;
        int n = b * BS + t;
        if (n < N) {
            float4 zn = zw[n];
            float di = zn.w;
            float a0 = s_agg[0][t*3+0] + s_agg[1][t*3+0] + s_agg[2][t*3+0] + s_agg[3][t*3+0];
            float a1 = s_agg[0][t*3+1] + s_agg[1][t*3+1] + s_agg[2][t*3+1] + s_agg[3][t*3+1];
            float a2 = s_agg[0][t*3+2] + s_agg[1][t*3+2] + s_agg[2][t*3+2] + s_agg[3][t*3+2];
            s_agg[0][t*3+0] = di * (a0 + zn.x);
            s_agg[0][t*3+1] = di * (a1 + zn.y);
            s_agg[0][t*3+2] = di * (a2 + zn.z);
        }
    }
    __syncthreads();

    for (int i = threadIdx.x; i < BS * 16; i += 1024) {
        int nl = i >> 4, j4 = (i & 15) << 2;
        int n = b * BS + nl;
        if (n >= N) continue;
        float a0 = s_agg[0][nl*3+0], a1 = s_agg[0][nl*3+1], a2 = s_agg[0][nl*3+2];
        float4 o;
        o.x = a0 * s_wa0[j4+0] + a1 * s_wa1[j4+0] + a2 * s_wa2[j4+0] + s_bb[j4+0];
        o.y = a0 * s_wa0[j4+1] + a1 * s_wa1[j4+1] + a2 * s_wa2[j4+1] + s_bb[j4+1];
        o.z = a0 * s_wa0[j4+2] + a1 * s_wa1[j4+2] + a2 * s_wa2[j4+2] + s_bb[j4+2];
        o.w = a0 * s_wa0[j4+3] + a1 * s_wa1[j4+3] + a2 * s_wa2[j4+3] + s_bb[j4+3];
        *reinterpret_cast<float4*>(out + (size_t)n * OUT_DIM + j4) = o;
    }
}

// ---------------------------------------------------------------------------
// Fallback (R1 path, shape-robust): detect + global-atomic deg/scatter + out.
__global__ void detect_kernel(const int* __restrict__ idx, int nsample, int* flag) {
    __shared__ int s_nz;
    if (threadIdx.x == 0) s_nz = 0;
    __syncthreads();
    int nz = 0;
    for (int i = threadIdx.x; i < nsample; i += blockDim.x) nz |= idx[2 * i + 1];
    if (nz) s_nz = 1;
    __syncthreads();
    if (threadIdx.x == 0) *flag = (s_nz == 0) ? 1 : 0;
}
__global__ void deg_kernel(const int* __restrict__ idx, int E,
                           const int* __restrict__ flag, float* __restrict__ deg) {
    int stride = (*flag) ? 2 : 1;
    const int* rowp = idx;
    const int* colp = idx + (size_t)E * stride;
    int step = gridDim.x * blockDim.x;
    for (int e = blockIdx.x * blockDim.x + threadIdx.x; e < E; e += step) {
        int r = rowp[(size_t)e * stride];
        int c = colp[(size_t)e * stride];
        if (r != c) atomicAdd(&deg[c], 1.0f);
    }
}
__global__ void dinv_self_kernel(const float4* __restrict__ z4, const float* __restrict__ deg,
                                 float* __restrict__ dinv, float* __restrict__ agg, int N) {
    int n = blockIdx.x * blockDim.x + threadIdx.x;
    if (n >= N) return;
    float d = deg[n] + 1.0f;
    float di = rsqrtf(d);
    dinv[n] = di;
    float w = 1.0f / d;
    float4 zn = z4[n];
    agg[(size_t)n * 3 + 0] = w * zn.x;
    agg[(size_t)n * 3 + 1] = w * zn.y;
    agg[(size_t)n * 3 + 2] = w * zn.z;
}
__global__ void scatter_kernel(const int* __restrict__ idx, int E,
                               const int* __restrict__ flag,
                               const float4* __restrict__ z4,
                               const float* __restrict__ dinv,
                               float* __restrict__ agg) {
    int stride = (*flag) ? 2 : 1;
    const int* rowp = idx;
    const int* colp = idx + (size_t)E * stride;
    int step = gridDim.x * blockDim.x;
    for (int e = blockIdx.x * blockDim.x + threadIdx.x; e < E; e += step) {
        int r = rowp[(size_t)e * stride];
        int c = colp[(size_t)e * stride];
        if (r != c) {
            float w = dinv[r] * dinv[c];
            float4 zr = z4[r];
            atomicAdd(&agg[(size_t)c * 3 + 0], w * zr.x);
            atomicAdd(&agg[(size_t)c * 3 + 1], w * zr.y);
            atomicAdd(&agg[(size_t)c * 3 + 2], w * zr.z);
        }
    }
}
__global__ void out_kernel(const float* __restrict__ agg,
                           const float* __restrict__ WA,
                           const float* __restrict__ bias,
                           float* __restrict__ out, int N) {
    int t = blockIdx.x * blockDim.x + threadIdx.x;
    int n = t >> 6;
    int j = t & 63;
    if (n >= N) return;
    float a0 = agg[(size_t)n * 3 + 0];
    float a1 = agg[(size_t)n * 3 + 1];
    float a2 = agg[(size_t)n * 3 + 2];
    out[(size_t)n * OUT_DIM + j] =
        a0 * WA[j * 3 + 0] + a1 * WA[j * 3 + 1] + a2 * WA[j * 3 + 2] + bias[j];
}

extern "C" void kernel_launch(void* const* d_in, const int* in_sizes, int n_in,
                              void* d_out, int out_size, void* d_ws, size_t ws_size,
                              hipStream_t stream) {
    const float* x    = (const float*)d_in[0];
    const int*   idx  = (const int*)d_in[1];
    const float* WB   = (const float*)d_in[2];
    const float* WA   = (const float*)d_in[3];
    const float* bias = (const float*)d_in[4];
    float* out = (float*)d_out;

    const int N = in_sizes[0] / IN_DIM;     // 100000
    const int E = in_sizes[1] / 2;          // 1600000

    auto align256 = [](size_t o) { return (o + 255) & ~(size_t)255; };
    char* ws = (char*)d_ws;
    size_t off = 0;
    int*    flag = (int*)(ws + off);    off = align256(off + sizeof(int));
    int*    gcur = (int*)(ws + off);    off = align256(off + NB * sizeof(int));
    float4* z4   = (float4*)(ws + off); off = align256(off + (size_t)N * sizeof(float4));
    float4* zw   = (float4*)(ws + off); off = align256(off + (size_t)N * sizeof(float4));
    float*  dinv = (float*)(ws + off);  off = align256(off + (size_t)N * sizeof(float));
    unsigned* recs = (unsigned*)(ws + off); off = align256(off + (size_t)NB * CAP2 * sizeof(unsigned));
    // fallback reuses fast-path regions
    float* degF = (float*)zw;
    float* aggF = (float*)recs;            // N*3 floats fit in recs region (8MB)

    const bool fast = (N <= NB * BS) && (N < (1 << 23)) && (ws_size >= off);

    int nsample = E < 1024 ? E : 1024;

    if (fast) {
        hipMemsetAsync(gcur, 0, NB * sizeof(int), stream);
        int nbin = (E + CHUNK - 1) / CHUNK;
        int nzp  = (N + 15) / 16;           // 16 nodes per 256-thread block
        k1_zproj_bin<<<nbin + nzp, 256, 0, stream>>>(x, WB, z4, N, idx, E, nsample,
                                                     recs, gcur, nbin);
        k2_zw<<<NB, 1024, 0, stream>>>(recs, gcur, z4, zw, N);
        k3_aggout<<<NB, 1024, 0, stream>>>(recs, gcur, zw, WA, bias, out, N);
    } else {
        detect_kernel<<<1, 256, 0, stream>>>(idx, nsample, flag);
        k1_zproj_bin<<<(N + 15) / 16, 256, 0, stream>>>(x, WB, z4, N, idx, E, nsample,
                                                        (unsigned*)aggF, gcur, 0);
        hipMemsetAsync(degF, 0, (size_t)N * sizeof(float), stream);
        deg_kernel<<<2048, 256, 0, stream>>>(idx, E, flag, degF);
        dinv_self_kernel<<<(N + 255) / 256, 256, 0, stream>>>(z4, degF, dinv, aggF, N);
        scatter_kernel<<<2048, 256, 0, stream>>>(idx, E, flag, z4, dinv, aggF);
        long long total = (long long)N * OUT_DIM;
        out_kernel<<<(int)((total + 255) / 256), 256, 0, stream>>>(aggF, WA, bias, out, N);
    }
}